// Round 13
// baseline (3336.290 us; speedup 1.0000x reference)
//
#include <hip/hip_runtime.h>
#include <hip/hip_bf16.h>
#include <cstdint>
#include <cstddef>

// ============================================================================
// EchoStateNetwork: h_{t+1} = 0.5*tanh(h_t @ W + U[t]) + 0.5*h_t
// U precomputed via 3-term bf16 MFMA GEMM (prep_u2).
// R13: swapped-operand scan — z^T = mfma(W^T_tile, h_rows). 128 WGs =
// 8 groups x 16 WGs x 4 waves; each WAVE owns 16 cols with full K=1024:
// no cross-wave LDS reduce, no syncthreads in the loop, per-wave flags
// (64 slots/group). XCD-local protocol (R9/R11-proven): plain h stores to
// local L2, vmcnt(1) drain, flag store, 64-slot ALD poll, one buffer_inv.
// Fallback (non-uniform placement): R8 L3 protocol, wave-decoupled.
//
// ws layout:
//   Whi [1024 n][1024 k] bf16 (= W^T)                           2 MB
//   U   [512 t][32 b][1024 n] f32                              64 MB
//   Hb2 [2][128 row][1024 col] bf16                           512 KB
//   bar census[8]/cb/claim[8] (256B apart) + flags[8][64]      16 KB
// ============================================================================

typedef unsigned short u16;
typedef unsigned int   u32;
typedef unsigned long long u64;
typedef __bf16 bf16x8 __attribute__((ext_vector_type(8)));
typedef u64    u64x2  __attribute__((ext_vector_type(2)));
typedef float  f32x4  __attribute__((ext_vector_type(4)));

#define T_STEPS 512
#define NWG     128
#define TPB     256

#define OFF_WHI 0
#define OFF_U   (2*1024*1024)
#define OFF_HB  (OFF_U + (size_t)512*32*1024*4)
#define HB_BYTES ((size_t)128*2048)             // 256 KB per buffer
#define OFF_BAR (OFF_HB + 2*HB_BYTES)
// bar (u32 idx): census[x]=x*64, cb=512, claim[x]=(9+x)*64, flags[g]=2048+g*64

__device__ __forceinline__ u16 f2bf(float f) {
  u32 u = __builtin_bit_cast(u32, f);
  u += 0x7fffu + ((u >> 16) & 1u);          // RNE
  return (u16)(u >> 16);
}
__device__ __forceinline__ float bf2f(u16 h) {
  u32 u = ((u32)h) << 16;
  return __builtin_bit_cast(float, u);
}
__device__ __forceinline__ void pinv(bf16x8& v) { asm volatile("" : "+v"(v)); }

__device__ __forceinline__ u32 AADD(u32* p, u32 v) {
  return __hip_atomic_fetch_add(p, v, __ATOMIC_RELAXED, __HIP_MEMORY_SCOPE_AGENT);
}
__device__ __forceinline__ u32 ALD(const u32* p) {
  return __hip_atomic_load(p, __ATOMIC_RELAXED, __HIP_MEMORY_SCOPE_AGENT);
}
__device__ __forceinline__ u64 ALD64(const u64* p) {
  return __hip_atomic_load(p, __ATOMIC_RELAXED, __HIP_MEMORY_SCOPE_AGENT);
}
__device__ __forceinline__ void AST(u32* p, u32 v) {
  __hip_atomic_store(p, v, __ATOMIC_RELAXED, __HIP_MEMORY_SCOPE_AGENT);
}

// --- prep: Whi[n][k] = bf16(W[k][n]) ----------------------------------------
__global__ void prep_w(const float* __restrict__ W, u16* __restrict__ whi) {
  int n = blockIdx.y;
  int k = blockIdx.x * 256 + threadIdx.x;
  whi[n * 1024 + k] = f2bf(W[k * 1024 + n]);
}

// --- prep_u2: U[m=t*32+b][n] = sum_k A[m][k]*Wi[n][k], 3-term bf16 MFMA ----
__global__ void __launch_bounds__(256) prep_u2(const float* __restrict__ x,
                                               const float* __restrict__ Wi,
                                               float* __restrict__ U) {
  __shared__ __align__(16) u16 Ah[128 * 128];   // 32 KB, XOR-swizzled
  __shared__ __align__(16) u16 Al[128 * 128];   // 32 KB
  const int tid = threadIdx.x;
  const int m0 = blockIdx.x << 7;
  const int n0 = blockIdx.y << 7;
  const int wv = tid >> 6, lane = tid & 63;
  const int fc = lane & 15, kb = lane >> 4;

  f32x4 acc[8][2];
#pragma unroll
  for (int mt = 0; mt < 8; ++mt) {
    acc[mt][0] = (f32x4){0.f, 0.f, 0.f, 0.f};
    acc[mt][1] = (f32x4){0.f, 0.f, 0.f, 0.f};
  }

  for (int hf = 0; hf < 2; ++hf) {
    __syncthreads();
#pragma unroll
    for (int s = 0; s < 16; ++s) {
      int f = (s << 8) + tid;
      int row = f >> 5, v = f & 31;
      int cl = v >> 4, i4 = (v & 15) << 2;
      int b = row & 31, t = (m0 + row) >> 5;
      float4 xv = *(const float4*)(x +
          ((size_t)((b << 2) | ((hf << 1) | cl)) * 512 + t) * 64 + i4);
      int byte = (row << 8) + (((cl << 7) + (i4 << 1)) ^ ((row & 7) << 4));
      u16* ph = (u16*)((char*)Ah + byte);
      u16* pl = (u16*)((char*)Al + byte);
      float vv[4] = {xv.x, xv.y, xv.z, xv.w};
#pragma unroll
      for (int e = 0; e < 4; ++e) {
        u16 hh = f2bf(vv[e]);
        ph[e] = hh;
        pl[e] = f2bf(vv[e] - bf2f(hh));
      }
    }
    bf16x8 Bh[2][4], Bl[2][4];
#pragma unroll
    for (int nt = 0; nt < 2; ++nt) {
      const float* wrow = Wi + (size_t)(n0 + (wv << 5) + (nt << 4) + fc) * 256;
#pragma unroll
      for (int kt = 0; kt < 4; ++kt) {
        int k = (hf << 7) + (kt << 5) + (kb << 3);
        float tmp[8];
        *(float4*)&tmp[0] = *(const float4*)(wrow + k);
        *(float4*)&tmp[4] = *(const float4*)(wrow + k + 4);
#pragma unroll
        for (int e = 0; e < 8; ++e) {
          u16 hh = f2bf(tmp[e]);
          Bh[nt][kt][e] = __builtin_bit_cast(__bf16, hh);
          Bl[nt][kt][e] = __builtin_bit_cast(__bf16, f2bf(tmp[e] - bf2f(hh)));
        }
      }
    }
    __syncthreads();
#pragma unroll
    for (int kt = 0; kt < 4; ++kt) {
      int kbyte = (kt << 6) + (kb << 4);
#pragma unroll
      for (int mt = 0; mt < 8; ++mt) {
        int row = (mt << 4) + fc;
        int byte = (row << 8) + (kbyte ^ ((row & 7) << 4));
        bf16x8 ah = *(const bf16x8*)((char*)Ah + byte);
        bf16x8 al = *(const bf16x8*)((char*)Al + byte);
#pragma unroll
        for (int nt = 0; nt < 2; ++nt) {
          acc[mt][nt] = __builtin_amdgcn_mfma_f32_16x16x32_bf16(ah, Bh[nt][kt], acc[mt][nt], 0, 0, 0);
          acc[mt][nt] = __builtin_amdgcn_mfma_f32_16x16x32_bf16(al, Bh[nt][kt], acc[mt][nt], 0, 0, 0);
          acc[mt][nt] = __builtin_amdgcn_mfma_f32_16x16x32_bf16(ah, Bl[nt][kt], acc[mt][nt], 0, 0, 0);
        }
      }
    }
  }
#pragma unroll
  for (int mt = 0; mt < 8; ++mt) {
    int mbase = m0 + (mt << 4) + (kb << 2);
    int n = n0 + (wv << 5) + fc;
#pragma unroll
    for (int nt = 0; nt < 2; ++nt)
#pragma unroll
      for (int r = 0; r < 4; ++r)
        U[(size_t)(mbase + r) * 1024 + n + (nt << 4)] = acc[mt][nt][r];
  }
}

// --- the scan ---------------------------------------------------------------
__global__ void __launch_bounds__(TPB, 1) esn_scan(
    const u16* __restrict__ Whi, const float* __restrict__ U,
    u16* __restrict__ Hb, float* __restrict__ out, u32* __restrict__ bar) {
  __shared__ int sh_q, sh_j, sh_loc;

  const int tid = threadIdx.x;
  const int wv = tid >> 6, lane = tid & 63;
  const int fc = lane & 15, kb = lane >> 4;

  // ---- census + role claim (one syncthreads, init only) -------------------
  if (tid == 0) {
    int xcd;
    asm volatile("s_getreg_b32 %0, hwreg(HW_REG_XCC_ID)" : "=s"(xcd));
    xcd &= 7;
    AADD(bar + xcd * 64, 1u);
    AADD(bar + 512, 1u);
    while (ALD(bar + 512) < (u32)NWG) __builtin_amdgcn_s_sleep(2);
    bool uni = true;
    for (int k = 0; k < 8; ++k) uni &= (ALD(bar + k * 64) == 16u);
    if (uni) {
      sh_q = xcd;
      sh_j = (int)AADD(bar + (9 + xcd) * 64, 1u);
      sh_loc = 1;
    } else {
      sh_q = blockIdx.x & 7;
      sh_j = blockIdx.x >> 3;
      sh_loc = 0;
    }
  }
  __syncthreads();
  const int q = sh_q, j = sh_j;
  const bool xlocal = (sh_loc != 0);
  const int r0 = q << 4;
  const int n0w = (j << 6) + (wv << 4);     // wave's 16-col base

  // ---- W^T A-fragments: 32 frags = 128 VGPRs, pinned ----------------------
  // A[m=fc][k = kt*32 + kb*8 + e] = Whi[n0w+fc][k]
  const char* wb = (const char*)Whi + (size_t)(n0w + fc) * 2048 + (kb << 4);
  bf16x8 wf[32];
#pragma unroll
  for (int kt = 0; kt < 32; ++kt)
    wf[kt] = *(const bf16x8*)(wb + (kt << 6));
#pragma unroll
  for (int kt = 0; kt < 32; ++kt) pinv(wf[kt]);

  // ---- per-lane outputs: row = r0+fc, cols ncol..ncol+3 -------------------
  const int grow = r0 + fc;
  const int ncol = n0w + (kb << 2);
  u32* flags = bar + 2048 + q * 64;         // 64 slots (2 lines) per group
  const int slot = (j << 2) + wv;

  float hreg[4] = {0.f, 0.f, 0.f, 0.f};
  f32x4 uf = *(const f32x4*)(U + (size_t)(grow >> 2) * 1024 + ncol);

  for (int t = 0; t < T_STEPS; ++t) {
    // ---- B-fragments of h: B[k][col=fc] = h[r0+fc][k] -----------------------
    const char* hsrc = (const char*)Hb + (size_t)(t & 1) * HB_BYTES
                       + (size_t)grow * 2048 + (kb << 4);
    bf16x8 hf[32];
    if (xlocal) {
#pragma unroll
      for (int kt = 0; kt < 32; ++kt)
        hf[kt] = *(const bf16x8*)(hsrc + (kt << 6));   // plain: local L2
    } else {
#pragma unroll
      for (int kt = 0; kt < 32; ++kt) {
        u64x2 p;
        p.x = ALD64((const u64*)(hsrc + (kt << 6)));
        p.y = ALD64((const u64*)(hsrc + (kt << 6) + 8));
        hf[kt] = __builtin_bit_cast(bf16x8, p);
      }
    }

    // ---- z^T tile: D[n-sub][row], 4 acc chains over k -----------------------
    f32x4 a0 = {0.f, 0.f, 0.f, 0.f}, a1 = {0.f, 0.f, 0.f, 0.f};
    f32x4 a2 = {0.f, 0.f, 0.f, 0.f}, a3 = {0.f, 0.f, 0.f, 0.f};
#pragma unroll
    for (int kt = 0; kt < 32; kt += 4) {
      a0 = __builtin_amdgcn_mfma_f32_16x16x32_bf16(wf[kt + 0], hf[kt + 0], a0, 0, 0, 0);
      a1 = __builtin_amdgcn_mfma_f32_16x16x32_bf16(wf[kt + 1], hf[kt + 1], a1, 0, 0, 0);
      a2 = __builtin_amdgcn_mfma_f32_16x16x32_bf16(wf[kt + 2], hf[kt + 2], a2, 0, 0, 0);
      a3 = __builtin_amdgcn_mfma_f32_16x16x32_bf16(wf[kt + 3], hf[kt + 3], a3, 0, 0, 0);
    }
    f32x4 z = (a0 + a1) + (a2 + a3);

    // ---- U prefetch for t+1 -------------------------------------------------
    f32x4 ufn = uf;
    if (t < T_STEPS - 1)
      ufn = *(const f32x4*)(U + ((size_t)(t + 1) * 32 + (grow >> 2)) * 1024 + ncol);

    // ---- epilogue: 4 outputs (row grow, cols ncol..+3) ----------------------
    f32x4 o;
    u64 pk = 0;
#pragma unroll
    for (int r = 0; r < 4; ++r) {
      float hn = 0.5f * tanhf(z[r] + uf[r]) + 0.5f * hreg[r];
      hreg[r] = hn;
      o[r] = hn;
      pk |= (u64)f2bf(hn) << (16 * r);
    }

    // ---- h store -> [vmcnt leaves out-store aging] -> flag ------------------
    u64* hdst = (u64*)((char*)Hb + (size_t)((t + 1) & 1) * HB_BYTES
                       + (size_t)grow * 2048 + (size_t)ncol * 2);
    __builtin_amdgcn_sched_barrier(0);
    if (xlocal) {
      *hdst = pk;                                     // plain: acks at local L2
    } else {
      (void)__hip_atomic_exchange(hdst, pk, __ATOMIC_RELAXED,
                                  __HIP_MEMORY_SCOPE_AGENT);
    }
    __builtin_amdgcn_sched_barrier(0);
    __builtin_nontemporal_store(o,
        (f32x4*)(out + ((size_t)grow * 512 + t) * 1024 + ncol));
    __builtin_amdgcn_sched_barrier(0);

    if (t < T_STEPS - 1) {
      // wait h-store (and older loads); out-store may stay outstanding
      asm volatile("s_waitcnt vmcnt(1)" ::: "memory");
      if (lane == 0) {
        if (xlocal) *(volatile u32*)(flags + slot) = (u32)(t + 1);
        else        AST(flags + slot, (u32)(t + 1));
      }
      // ---- poll all 64 wave-slots of the group ------------------------------
      u32 tgt = (u32)(t + 1);
      if (xlocal) {
        const u32* fp = flags + lane;
        while (true) {
          u32 v = ALD(fp);
          if (__all((int)(v >= tgt))) break;
        }
        asm volatile("buffer_inv\n\ts_waitcnt vmcnt(0)" ::: "memory");
      } else {
        while (true) {
          u32 v = ALD(flags + lane);
          if (__all((int)(v >= tgt))) break;
          __builtin_amdgcn_s_sleep(1);
        }
      }
    }
    uf = ufn;
  }
}

// ============================================================================
extern "C" void kernel_launch(void* const* d_in, const int* in_sizes, int n_in,
                              void* d_out, int out_size, void* d_ws, size_t ws_size,
                              hipStream_t stream) {
  (void)in_sizes; (void)n_in; (void)out_size; (void)ws_size;
  const float* x  = (const float*)d_in[0];   // [32,4,512,64]
  const float* Wi = (const float*)d_in[1];   // [1024,256]
  const float* W  = (const float*)d_in[2];   // [1024,1024]
  float* out = (float*)d_out;                // [32,4,512,1024]

  char* ws  = (char*)d_ws;
  u16*  whi = (u16*)(ws + OFF_WHI);
  float* U  = (float*)(ws + OFF_U);
  u16*  hb  = (u16*)(ws + OFF_HB);
  u32*  bar = (u32*)(ws + OFF_BAR);

  // zero h0 double-buffer + census/claim/flag region (monotonic per launch)
  (void)hipMemsetAsync(ws + OFF_HB, 0, 2 * HB_BYTES + 16384, stream);

  hipLaunchKernelGGL(prep_w, dim3(4, 1024), dim3(256), 0, stream, W, whi);
  hipLaunchKernelGGL(prep_u2, dim3(128, 8), dim3(256), 0, stream, x, Wi, U);
  hipLaunchKernelGGL(esn_scan, dim3(NWG), dim3(TPB), 0, stream,
                     whi, U, hb, out, bar);
}

// Round 14
// 1861.857 us; speedup vs baseline: 1.7919x; 1.7919x over previous
//
#include <hip/hip_runtime.h>
#include <hip/hip_bf16.h>
#include <cstdint>
#include <cstddef>

// ============================================================================
// EchoStateNetwork: h_{t+1} = 0.5*tanh(h_t @ W + U[t]) + 0.5*h_t
// U precomputed via 3-term bf16 MFMA GEMM (prep_u2).
// R14: 128 WGs = 8 groups(XCD-local) x 16 WGs. WG = 16 rows x 64 cols;
// 4 waves split K=1024 (8 frags each); W = 32 frags = 128 VGPR pinned/wave.
// h loads = ALD64 (agent, L1-bypass; served by local L2 for dirty lines —
// proven by the R9-R12 flag path). NO buffer_inv anywhere in the loop.
// Barrier: stores -> syncthreads(vmcnt0) -> tid0 flag -> wave0 polls 16
// slots -> syncthreads. Fallback = R8 L3 protocol (swap stores + sleep poll).
//
// ws layout:
//   Whi [1024 n][1024 k] bf16 (= W^T)                           2 MB
//   U   [512 t][32 b][1024 n] f32                              64 MB
//   Hb2 [2][128 row][1024 col] bf16                           512 KB
//   bar census[8]/cb/claim[8] (256B apart) + flags[8][64]      16 KB
// ============================================================================

typedef unsigned short u16;
typedef unsigned int   u32;
typedef unsigned long long u64;
typedef __bf16 bf16x8 __attribute__((ext_vector_type(8)));
typedef u64    u64x2  __attribute__((ext_vector_type(2)));
typedef float  f32x4  __attribute__((ext_vector_type(4)));

#define T_STEPS 512
#define NWG     128
#define TPB     256

#define OFF_WHI 0
#define OFF_U   (2*1024*1024)
#define OFF_HB  (OFF_U + (size_t)512*32*1024*4)
#define HB_BYTES ((size_t)128*2048)             // 256 KB per buffer
#define OFF_BAR (OFF_HB + 2*HB_BYTES)
// bar (u32 idx): census[x]=x*64, cb=512, claim[x]=(9+x)*64, flags[g]=2048+g*64

__device__ __forceinline__ u16 f2bf(float f) {
  u32 u = __builtin_bit_cast(u32, f);
  u += 0x7fffu + ((u >> 16) & 1u);          // RNE
  return (u16)(u >> 16);
}
__device__ __forceinline__ float bf2f(u16 h) {
  u32 u = ((u32)h) << 16;
  return __builtin_bit_cast(float, u);
}
__device__ __forceinline__ void pinv(bf16x8& v) { asm volatile("" : "+v"(v)); }

__device__ __forceinline__ u32 AADD(u32* p, u32 v) {
  return __hip_atomic_fetch_add(p, v, __ATOMIC_RELAXED, __HIP_MEMORY_SCOPE_AGENT);
}
__device__ __forceinline__ u32 ALD(const u32* p) {
  return __hip_atomic_load(p, __ATOMIC_RELAXED, __HIP_MEMORY_SCOPE_AGENT);
}
__device__ __forceinline__ u64 ALD64(const u64* p) {
  return __hip_atomic_load(p, __ATOMIC_RELAXED, __HIP_MEMORY_SCOPE_AGENT);
}
__device__ __forceinline__ void AST(u32* p, u32 v) {
  __hip_atomic_store(p, v, __ATOMIC_RELAXED, __HIP_MEMORY_SCOPE_AGENT);
}

// --- prep: Whi[n][k] = bf16(W[k][n]) ----------------------------------------
__global__ void prep_w(const float* __restrict__ W, u16* __restrict__ whi) {
  int n = blockIdx.y;
  int k = blockIdx.x * 256 + threadIdx.x;
  whi[n * 1024 + k] = f2bf(W[k * 1024 + n]);
}

// --- prep_u2: U[m=t*32+b][n] = sum_k A[m][k]*Wi[n][k], 3-term bf16 MFMA ----
__global__ void __launch_bounds__(256) prep_u2(const float* __restrict__ x,
                                               const float* __restrict__ Wi,
                                               float* __restrict__ U) {
  __shared__ __align__(16) u16 Ah[128 * 128];   // 32 KB, XOR-swizzled
  __shared__ __align__(16) u16 Al[128 * 128];   // 32 KB
  const int tid = threadIdx.x;
  const int m0 = blockIdx.x << 7;
  const int n0 = blockIdx.y << 7;
  const int wv = tid >> 6, lane = tid & 63;
  const int fc = lane & 15, kb = lane >> 4;

  f32x4 acc[8][2];
#pragma unroll
  for (int mt = 0; mt < 8; ++mt) {
    acc[mt][0] = (f32x4){0.f, 0.f, 0.f, 0.f};
    acc[mt][1] = (f32x4){0.f, 0.f, 0.f, 0.f};
  }

  for (int hf = 0; hf < 2; ++hf) {
    __syncthreads();
#pragma unroll
    for (int s = 0; s < 16; ++s) {
      int f = (s << 8) + tid;
      int row = f >> 5, v = f & 31;
      int cl = v >> 4, i4 = (v & 15) << 2;
      int b = row & 31, t = (m0 + row) >> 5;
      float4 xv = *(const float4*)(x +
          ((size_t)((b << 2) | ((hf << 1) | cl)) * 512 + t) * 64 + i4);
      int byte = (row << 8) + (((cl << 7) + (i4 << 1)) ^ ((row & 7) << 4));
      u16* ph = (u16*)((char*)Ah + byte);
      u16* pl = (u16*)((char*)Al + byte);
      float vv[4] = {xv.x, xv.y, xv.z, xv.w};
#pragma unroll
      for (int e = 0; e < 4; ++e) {
        u16 hh = f2bf(vv[e]);
        ph[e] = hh;
        pl[e] = f2bf(vv[e] - bf2f(hh));
      }
    }
    bf16x8 Bh[2][4], Bl[2][4];
#pragma unroll
    for (int nt = 0; nt < 2; ++nt) {
      const float* wrow = Wi + (size_t)(n0 + (wv << 5) + (nt << 4) + fc) * 256;
#pragma unroll
      for (int kt = 0; kt < 4; ++kt) {
        int k = (hf << 7) + (kt << 5) + (kb << 3);
        float tmp[8];
        *(float4*)&tmp[0] = *(const float4*)(wrow + k);
        *(float4*)&tmp[4] = *(const float4*)(wrow + k + 4);
#pragma unroll
        for (int e = 0; e < 8; ++e) {
          u16 hh = f2bf(tmp[e]);
          Bh[nt][kt][e] = __builtin_bit_cast(__bf16, hh);
          Bl[nt][kt][e] = __builtin_bit_cast(__bf16, f2bf(tmp[e] - bf2f(hh)));
        }
      }
    }
    __syncthreads();
#pragma unroll
    for (int kt = 0; kt < 4; ++kt) {
      int kbyte = (kt << 6) + (kb << 4);
#pragma unroll
      for (int mt = 0; mt < 8; ++mt) {
        int row = (mt << 4) + fc;
        int byte = (row << 8) + (kbyte ^ ((row & 7) << 4));
        bf16x8 ah = *(const bf16x8*)((char*)Ah + byte);
        bf16x8 al = *(const bf16x8*)((char*)Al + byte);
#pragma unroll
        for (int nt = 0; nt < 2; ++nt) {
          acc[mt][nt] = __builtin_amdgcn_mfma_f32_16x16x32_bf16(ah, Bh[nt][kt], acc[mt][nt], 0, 0, 0);
          acc[mt][nt] = __builtin_amdgcn_mfma_f32_16x16x32_bf16(al, Bh[nt][kt], acc[mt][nt], 0, 0, 0);
          acc[mt][nt] = __builtin_amdgcn_mfma_f32_16x16x32_bf16(ah, Bl[nt][kt], acc[mt][nt], 0, 0, 0);
        }
      }
    }
  }
#pragma unroll
  for (int mt = 0; mt < 8; ++mt) {
    int mbase = m0 + (mt << 4) + (kb << 2);
    int n = n0 + (wv << 5) + fc;
#pragma unroll
    for (int nt = 0; nt < 2; ++nt)
#pragma unroll
      for (int r = 0; r < 4; ++r)
        U[(size_t)(mbase + r) * 1024 + n + (nt << 4)] = acc[mt][nt][r];
  }
}

// --- the scan ---------------------------------------------------------------
__global__ void __launch_bounds__(TPB, 1) esn_scan(
    const u16* __restrict__ Whi, const float* __restrict__ U,
    u16* __restrict__ Hb, float* __restrict__ out, u32* __restrict__ bar) {
  __shared__ __align__(16) float red[4 * 4 * 64 * 4];   // [wv][nt][lane][r] 16 KB
  __shared__ int sh_q, sh_j, sh_loc;

  const int tid = threadIdx.x;
  const int wv = tid >> 6, lane = tid & 63;
  const int mrow = lane & 15, kb = lane >> 4;   // A-frag: h-row, k-subblock

  // ---- census + role claim -------------------------------------------------
  if (tid == 0) {
    int xcd;
    asm volatile("s_getreg_b32 %0, hwreg(HW_REG_XCC_ID)" : "=s"(xcd));
    xcd &= 7;
    AADD(bar + xcd * 64, 1u);
    AADD(bar + 512, 1u);
    while (ALD(bar + 512) < (u32)NWG) __builtin_amdgcn_s_sleep(2);
    bool uni = true;
    for (int k = 0; k < 8; ++k) uni &= (ALD(bar + k * 64) == 16u);
    if (uni) {
      sh_q = xcd;
      sh_j = (int)AADD(bar + (9 + xcd) * 64, 1u);
      sh_loc = 1;
    } else {
      sh_q = blockIdx.x & 7;
      sh_j = blockIdx.x >> 3;
      sh_loc = 0;
    }
  }
  __syncthreads();
  const int q = sh_q, j = sh_j;
  const bool xlocal = (sh_loc != 0);
  const int r0 = q << 4, c0 = j << 6;       // 16 rows, 64 cols

  // ---- W B-fragments: [ntile 4][kt 8] = 128 VGPRs, pinned -----------------
  bf16x8 bh[4][8];
#pragma unroll
  for (int nt = 0; nt < 4; ++nt) {
    const char* wb = (const char*)Whi + (size_t)(c0 + nt * 16 + mrow) * 2048
                     + wv * 512 + kb * 16;
#pragma unroll
    for (int kt = 0; kt < 8; ++kt)
      bh[nt][kt] = *(const bf16x8*)(wb + kt * 64);
  }
#pragma unroll
  for (int nt = 0; nt < 4; ++nt)
#pragma unroll
    for (int kt = 0; kt < 8; ++kt) pinv(bh[nt][kt]);

  // ---- per-thread output mapping: 4 outputs (row, 4 consecutive cols) -----
  const int row_l = tid >> 4;               // 0..15
  const int col4  = (tid & 15) << 2;        // 0..60
  const int grow  = r0 + row_l;
  const int ont   = col4 >> 4, ofc = col4 & 15;
  const int okb   = row_l >> 2, orr = row_l & 3;
  u32* flags = bar + 2048 + q * 64;         // 16 slots used per group

  float hreg[4] = {0.f, 0.f, 0.f, 0.f};
  f32x4 uf = *(const f32x4*)(U + (size_t)(grow >> 2) * 1024 + c0 + col4);

  for (int t = 0; t < T_STEPS; ++t) {
    // ---- A-fragments of h via ALD64 (L1-bypass; local-L2 hit) --------------
    const char* hsrc = (const char*)Hb + (size_t)(t & 1) * HB_BYTES
                       + (size_t)(r0 + mrow) * 2048 + wv * 512 + kb * 16;
    bf16x8 av[8];
#pragma unroll
    for (int kt = 0; kt < 8; ++kt) {
      u64x2 p;
      p.x = ALD64((const u64*)(hsrc + kt * 64));
      p.y = ALD64((const u64*)(hsrc + kt * 64 + 8));
      av[kt] = __builtin_bit_cast(bf16x8, p);
    }
    // U prefetch for t+1 (completes during compute)
    f32x4 ufn = uf;
    if (t < T_STEPS - 1)
      ufn = *(const f32x4*)(U + ((size_t)(t + 1) * 32 + (grow >> 2)) * 1024 + c0 + col4);

    // ---- z partial: 4 acc chains over ntiles --------------------------------
    f32x4 acc[4];
#pragma unroll
    for (int nt = 0; nt < 4; ++nt) acc[nt] = (f32x4){0.f, 0.f, 0.f, 0.f};
#pragma unroll
    for (int kt = 0; kt < 8; ++kt) {
#pragma unroll
      for (int nt = 0; nt < 4; ++nt)
        acc[nt] = __builtin_amdgcn_mfma_f32_16x16x32_bf16(av[kt], bh[nt][kt], acc[nt], 0, 0, 0);
    }

    // ---- cross-wave K reduction via LDS ------------------------------------
#pragma unroll
    for (int nt = 0; nt < 4; ++nt)
      *(f32x4*)&red[((wv * 4 + nt) * 64 + lane) * 4] = acc[nt];
    __syncthreads();

    // ---- epilogue: 4 outputs ------------------------------------------------
    f32x4 z = {0.f, 0.f, 0.f, 0.f};
#pragma unroll
    for (int w = 0; w < 4; ++w) {
#pragma unroll
      for (int i = 0; i < 4; ++i)
        z[i] += red[((w * 4 + ont) * 64 + okb * 16 + ofc + i) * 4 + orr];
    }
    f32x4 o;
    u64 pk = 0;
#pragma unroll
    for (int r = 0; r < 4; ++r) {
      float hn = 0.5f * tanhf(z[r] + uf[r]) + 0.5f * hreg[r];
      hreg[r] = hn;
      o[r] = hn;
      pk |= (u64)f2bf(hn) << (16 * r);
    }

    // ---- h store + out store ------------------------------------------------
    {
      u64* hdst = (u64*)((char*)Hb + (size_t)((t + 1) & 1) * HB_BYTES
                         + (size_t)grow * 2048 + (size_t)(c0 + col4) * 2);
      if (xlocal) {
        *hdst = pk;                                   // plain: acks at local L2
      } else {
        (void)__hip_atomic_exchange(hdst, pk, __ATOMIC_RELAXED,
                                    __HIP_MEMORY_SCOPE_AGENT);
      }
      __builtin_nontemporal_store(o,
          (f32x4*)(out + ((size_t)grow * 512 + t) * 1024 + c0 + col4));
    }
    __syncthreads();   // compiler emits vmcnt(0): all waves' stores in L2

    if (t < T_STEPS - 1) {
      if (tid == 0) {
        if (xlocal) *(volatile u32*)(flags + j) = (u32)(t + 1);
        else        AST(flags + j, (u32)(t + 1));
      }
      // ---- wave0 polls the group's 16 slots ----------------------------------
      if (wv == 0) {
        u32 tgt = (u32)(t + 1);
        if (xlocal) {
          const u32* fp = flags + (lane & 15);
          while (true) {
            u32 v = ALD(fp);
            if (__all((int)(v >= tgt))) break;
          }
        } else {
          while (true) {
            u32 v = ALD(flags + (lane & 15));
            if (__all((int)(v >= tgt))) break;
            __builtin_amdgcn_s_sleep(1);
          }
        }
      }
      __syncthreads();
    }
    uf = ufn;
  }
}

// ============================================================================
extern "C" void kernel_launch(void* const* d_in, const int* in_sizes, int n_in,
                              void* d_out, int out_size, void* d_ws, size_t ws_size,
                              hipStream_t stream) {
  (void)in_sizes; (void)n_in; (void)out_size; (void)ws_size;
  const float* x  = (const float*)d_in[0];   // [32,4,512,64]
  const float* Wi = (const float*)d_in[1];   // [1024,256]
  const float* W  = (const float*)d_in[2];   // [1024,1024]
  float* out = (float*)d_out;                // [32,4,512,1024]

  char* ws  = (char*)d_ws;
  u16*  whi = (u16*)(ws + OFF_WHI);
  float* U  = (float*)(ws + OFF_U);
  u16*  hb  = (u16*)(ws + OFF_HB);
  u32*  bar = (u32*)(ws + OFF_BAR);

  // zero h0 double-buffer + census/claim/flag region (monotonic per launch)
  (void)hipMemsetAsync(ws + OFF_HB, 0, 2 * HB_BYTES + 16384, stream);

  hipLaunchKernelGGL(prep_w, dim3(4, 1024), dim3(256), 0, stream, W, whi);
  hipLaunchKernelGGL(prep_u2, dim3(128, 8), dim3(256), 0, stream, x, Wi, U);
  hipLaunchKernelGGL(esn_scan, dim3(NWG), dim3(TPB), 0, stream,
                     whi, U, hb, out, bar);
}